// Round 8
// baseline (3539.288 us; speedup 1.0000x reference)
//
#include <hip/hip_runtime.h>
#include <hip/hip_bf16.h>
#include <cstddef>

// Problem constants
constexpr int B = 128;
constexpr int T = 500;
constexpr int C = 128;     // n_maps
constexpr int CIN = 80;    // n_mels
constexpr int NL = 35;     // labels
constexpr size_t NBCT = (size_t)B * C * T;  // 8,192,000 floats
constexpr int NPART = 1024;                 // partial-stats buffer stride
constexpr int WPAD = 132;                   // LDS i-stride (0 bank conflicts, measured R4)
constexpr int I0 = 96;                      // conv0 padded input channels
constexpr int IPAD0 = 104;                  // conv0 LDS i-stride
constexpr int NT = 64;                      // conv t-tile (4 blocks/CU resident)

typedef __attribute__((ext_vector_type(8))) short short8;    // 8 bf16
typedef __attribute__((ext_vector_type(4))) float f32x4;
typedef __attribute__((ext_vector_type(16))) float f32x16;

// Static device scratch. All activation tensors in [b][t][c] layout.
__device__ float g_z[NBCT];
__device__ float g_acc[NBCT];
__device__ float g_zin[NBCT];
__device__ float g_t1[NBCT];
__device__ float g_t2[NBCT];
__device__ float g_t3[NBCT];
__device__ float g_ps1[C * NPART], g_pq1[C * NPART];
__device__ float g_ps2[C * NPART], g_pq2[C * NPART];
__device__ float g_ps3[C * NPART], g_pq3[C * NPART];
__device__ float g_m1[C], g_r1[C], g_m2[C], g_r2[C], g_m3[C], g_r3[C];
__device__ float g_featp[B * 4 * C];        // head partial sums
// conv0 weights, layout [kw][o][i] (i-stride I0)
__device__ unsigned short g_w0h[3 * C * I0], g_w0l[3 * C * I0];
// main conv weights, MFMA-native layout [kw][kseg=i>>3][o][j=i&7]
__device__ unsigned short g_w1h[9 * C * C], g_w1l[9 * C * C];
__device__ unsigned short g_w2h[9 * C * C], g_w2l[9 * C * C];
__device__ unsigned short g_w3h[1 * C * C], g_w3l[1 * C * C];

__device__ inline unsigned short f2bf(float x) {
  __hip_bfloat16 h = __float2bfloat16(x);
  return *(unsigned short*)&h;
}
__device__ inline float bf2f(unsigned short u) {
  __hip_bfloat16 h = *(__hip_bfloat16*)&u;
  return __bfloat162float(h);
}
__device__ inline void split_bf16(float x, unsigned short& h, unsigned short& l) {
  unsigned short hh = f2bf(x);
  h = hh;
  l = f2bf(x - bf2f(hh));
}

__inline__ __device__ float wave_sum(float v) {
  for (int off = 32; off; off >>= 1) v += __shfl_down(v, off);
  return v;
}

// ---------------------------------------------------------------------------
// Weight prep: w [O][I][KW] fp32 -> hi/lo bf16, layout [kw][i>>3][o][i&7]
// ---------------------------------------------------------------------------
template <int KW>
__global__ __launch_bounds__(256) void prep_weights_v4(
    const float* __restrict__ w, unsigned short* __restrict__ wh,
    unsigned short* __restrict__ wl) {
  int idx = blockIdx.x * 256 + threadIdx.x;
  if (idx >= C * C * KW) return;
  int kw = idx % KW;
  int i = (idx / KW) % C;
  int o = idx / (KW * C);
  unsigned short h, l;
  split_bf16(w[idx], h, l);
  size_t dst = (((size_t)kw * 16 + (i >> 3)) * C + o) * 8 + (i & 7);
  wh[dst] = h;
  wl[dst] = l;
}

// conv0 weights: w0 [O=128][I=80][3] -> [3][O][I0=96] (zero-padded i>=80)
__global__ __launch_bounds__(256) void prep_w0(
    const float* __restrict__ w, unsigned short* __restrict__ wh,
    unsigned short* __restrict__ wl) {
  int idx = blockIdx.x * 256 + threadIdx.x;
  if (idx >= 3 * C * I0) return;
  int i = idx % I0;
  int o = (idx / I0) % C;
  int kw = idx / (I0 * C);
  unsigned short h = 0, l = 0;
  if (i < CIN) split_bf16(w[((size_t)o * CIN + i) * 3 + kw], h, l);
  size_t dst = ((size_t)kw * C + o) * I0 + i;
  wh[dst] = h;
  wl[dst] = l;
}

// ---------------------------------------------------------------------------
// Epilogue helper for 16x16x32 (conv0 only).
// ---------------------------------------------------------------------------
template <int NG, int NTG>
__device__ inline void store_and_stats(f32x4 (&dacc)[NG][NTG],
                                       float* __restrict__ outb,
                                       float* __restrict__ ssum,
                                       float* __restrict__ ssq, int tbase,
                                       int og0, int quad, int m15) {
#pragma unroll
  for (int g = 0; g < NG; g++) {
    float rs[4] = {0.f, 0.f, 0.f, 0.f}, rq[4] = {0.f, 0.f, 0.f, 0.f};
#pragma unroll
    for (int tg = 0; tg < NTG; tg++) {
      int t = tbase + tg * 16 + m15;
      bool valid = t < T;
      f32x4 d = dacc[g][tg];
      if (valid)
        *(f32x4*)(outb + (size_t)t * C + (og0 + g) * 16 + quad * 4) = d;
#pragma unroll
      for (int r = 0; r < 4; r++) {
        float v = valid ? d[r] : 0.f;
        rs[r] += v;
        rq[r] += v * v;
      }
    }
#pragma unroll
    for (int sh = 1; sh < 16; sh <<= 1) {
#pragma unroll
      for (int r = 0; r < 4; r++) {
        rs[r] += __shfl_xor(rs[r], sh);
        rq[r] += __shfl_xor(rq[r], sh);
      }
    }
    if (m15 == 0) {
      int o = (og0 + g) * 16 + quad * 4;
#pragma unroll
      for (int r = 0; r < 4; r++) {
        atomicAdd(&ssum[o + r], rs[r]);
        atomicAdd(&ssq[o + r], rq[r]);
      }
    }
  }
}

// ---------------------------------------------------------------------------
// Main MFMA conv v6: 32x32x16 bf16x3 in the proven NT=64 / 4-blocks-per-CU
// envelope. 4 waves; wave = (o-half, t-half): 2 o-tiles of 32 x 1 t-tile of
// 32. Per K16 chunk: 2x2 A loads + 1x2 B reads feed 6 MFMAs.
// ---------------------------------------------------------------------------
template <int KW, int PAD, bool BNRELU>
__global__ __launch_bounds__(256, 4) void conv_v6(
    const float* __restrict__ in, const unsigned short* __restrict__ wh,
    const unsigned short* __restrict__ wl, const float* __restrict__ bnm,
    const float* __restrict__ bnr, float* __restrict__ out,
    float* __restrict__ ps, float* __restrict__ pq) {
  constexpr int ROWS = NT + KW - 1;
  constexpr int ITERS = KW * 8;  // K16 chunks
  __shared__ __align__(16) unsigned short shi[ROWS * WPAD];
  __shared__ __align__(16) unsigned short slo[ROWS * WPAD];
  __shared__ float ssum[C], ssq[C];
  __shared__ float sbm[C], sbr[C];

  const int tid = threadIdx.x;
  const int tile = blockIdx.x;
  const int b = blockIdx.y;
  const int t0 = tile * NT;

  if (BNRELU) {
    if (tid < 128) { sbm[tid] = bnm[tid]; sbr[tid] = bnr[tid]; }
  }
  if (tid < 128) { ssum[tid] = 0.f; ssq[tid] = 0.f; }
  __syncthreads();

  // Stage input rows [t0-PAD, t0-PAD+ROWS) as bf16 hi/lo into LDS.
  const float* __restrict__ inb = in + (size_t)b * T * C;
  constexpr int NF4 = ROWS * (C / 4);
  for (int e = tid; e < NF4; e += 256) {
    int r = e >> 5;
    int c4 = e & 31;
    int t = t0 - PAD + r;
    float4 v = make_float4(0.f, 0.f, 0.f, 0.f);
    if (t >= 0 && t < T) v = ((const float4*)(inb + (size_t)t * C))[c4];
    if (BNRELU) {
      int c = c4 * 4;
      v.x = fmaxf((v.x - sbm[c]) * sbr[c], 0.f);
      v.y = fmaxf((v.y - sbm[c + 1]) * sbr[c + 1], 0.f);
      v.z = fmaxf((v.z - sbm[c + 2]) * sbr[c + 2], 0.f);
      v.w = fmaxf((v.w - sbm[c + 3]) * sbr[c + 3], 0.f);
    }
    ushort4 hv, lv;
    split_bf16(v.x, hv.x, lv.x);
    split_bf16(v.y, hv.y, lv.y);
    split_bf16(v.z, hv.z, lv.z);
    split_bf16(v.w, hv.w, lv.w);
    int off = r * WPAD + c4 * 4;
    *(ushort4*)&shi[off] = hv;
    *(ushort4*)&slo[off] = lv;
  }
  __syncthreads();

  const int wv = tid >> 6;
  const int lane = tid & 63;
  const int m32 = lane & 31;
  const int half = lane >> 5;
  const int ob = (wv & 1) * 64;   // o-base: 2 tiles (ob, ob+32)
  const int tb = (wv >> 1) * 32;  // t-base: one 32-tile

  const short8* __restrict__ Ah = (const short8*)wh;
  const short8* __restrict__ Al = (const short8*)wl;

  f32x16 dacc[2];
#pragma unroll
  for (int g = 0; g < 2; g++)
#pragma unroll
    for (int r = 0; r < 16; r++) dacc[g][r] = 0.f;

  for (int it = 0; it < ITERS; ++it) {
    const int kw = it >> 3, kc = it & 7;
    // A frags (lane: o=m32, k=half*8+j): index [kw][kc*2+half][o][j]
    short8 ah[2], al[2];
#pragma unroll
    for (int g = 0; g < 2; g++) {
      int ai = (kw * 16 + kc * 2 + half) * C + ob + g * 32 + m32;
      ah[g] = Ah[ai];
      al[g] = Al[ai];
    }
    // B frag (lane: t=m32, k=half*8+j): LDS row tb+m32+kw, col kc*16+half*8
    short8 bh, bl;
    {
      int off = (tb + m32 + kw) * WPAD + kc * 16 + half * 8;
      bh = *(const short8*)(shi + off);
      bl = *(const short8*)(slo + off);
    }
#pragma unroll
    for (int g = 0; g < 2; g++) {
      f32x16 d = dacc[g];
      d = __builtin_amdgcn_mfma_f32_32x32x16_bf16(ah[g], bh, d, 0, 0, 0);
      d = __builtin_amdgcn_mfma_f32_32x32x16_bf16(ah[g], bl, d, 0, 0, 0);
      d = __builtin_amdgcn_mfma_f32_32x32x16_bf16(al[g], bh, d, 0, 0, 0);
      dacc[g] = d;
    }
  }

  // Epilogue. 32x32 D layout: col(t)=lane&31, row(o)=(reg&3)+8*(reg>>2)+4*half
  float* __restrict__ outb = out + (size_t)b * T * C;
  const int t = t0 + tb + m32;
  const bool valid = t < T;
#pragma unroll
  for (int g = 0; g < 2; g++) {
    f32x16 d = dacc[g];
    if (valid) {
      float* op = outb + (size_t)t * C + ob + g * 32 + half * 4;
#pragma unroll
      for (int q = 0; q < 4; q++) {
        f32x4 v4 = {d[q * 4 + 0], d[q * 4 + 1], d[q * 4 + 2], d[q * 4 + 3]};
        *(f32x4*)(op + q * 8) = v4;
      }
    }
    float rs[16], rq[16];
#pragma unroll
    for (int r = 0; r < 16; r++) {
      float v = valid ? d[r] : 0.f;
      rs[r] = v;
      rq[r] = v * v;
    }
#pragma unroll
    for (int sh = 1; sh < 32; sh <<= 1) {
#pragma unroll
      for (int r = 0; r < 16; r++) {
        rs[r] += __shfl_xor(rs[r], sh);
        rq[r] += __shfl_xor(rq[r], sh);
      }
    }
    if (m32 == 0) {
#pragma unroll
      for (int q = 0; q < 4; q++)
#pragma unroll
        for (int rr = 0; rr < 4; rr++) {
          int o = ob + g * 32 + q * 8 + half * 4 + rr;
          atomicAdd(&ssum[o], rs[q * 4 + rr]);
          atomicAdd(&ssq[o], rq[q * 4 + rr]);
        }
    }
  }
  __syncthreads();
  int p = b * 8 + tile;
  if (tid < 128) {
    ps[tid * NPART + p] = ssum[tid];
    pq[tid * NPART + p] = ssq[tid];
  }
}

// ---------------------------------------------------------------------------
// conv0: 16x16x32 MFMA bf16x3. in x[B][80][T] (t fastest), K=96(pad) x 3.
// ---------------------------------------------------------------------------
__global__ __launch_bounds__(256) void conv0_mfma(
    const float* __restrict__ in, const unsigned short* __restrict__ wh,
    const unsigned short* __restrict__ wl, float* __restrict__ out,
    float* __restrict__ ps, float* __restrict__ pq) {
  constexpr int KW = 3, PAD = 1;
  constexpr int ROWS = NT + KW - 1;  // 66
  __shared__ __align__(16) unsigned short shi[ROWS * IPAD0];
  __shared__ __align__(16) unsigned short slo[ROWS * IPAD0];
  __shared__ float ssum[C], ssq[C];

  const int tid = threadIdx.x;
  const int tile = blockIdx.x;
  const int b = blockIdx.y;
  const int t0 = tile * NT;

  if (tid < 128) { ssum[tid] = 0.f; ssq[tid] = 0.f; }
  __syncthreads();

  const float* __restrict__ inb = in + (size_t)b * CIN * T;
  for (int e = tid; e < I0 * ROWS; e += 256) {
    int i = e / ROWS;
    int r = e % ROWS;
    int t = t0 - PAD + r;
    float v = 0.f;
    if (i < CIN && t >= 0 && t < T) v = inb[(size_t)i * T + t];
    unsigned short h, l;
    split_bf16(v, h, l);
    shi[r * IPAD0 + i] = h;
    slo[r * IPAD0 + i] = l;
  }
  __syncthreads();

  const int wv = tid >> 6;
  const int lane = tid & 63;
  const int quad = lane >> 4;
  const int m15 = lane & 15;
  const int og0 = wv * 2;

  f32x4 dacc[2][4];
#pragma unroll
  for (int g = 0; g < 2; g++)
#pragma unroll
    for (int tg = 0; tg < 4; tg++) dacc[g][tg] = f32x4{0.f, 0.f, 0.f, 0.f};

  for (int kw = 0; kw < KW; kw++) {
    const unsigned short* __restrict__ wkh = wh + (size_t)kw * C * I0;
    const unsigned short* __restrict__ wkl = wl + (size_t)kw * C * I0;
#pragma unroll
    for (int ic = 0; ic < 3; ic++) {
      const int kof = ic * 32 + quad * 8;
      short8 ah[2], al[2];
#pragma unroll
      for (int g = 0; g < 2; g++) {
        size_t off = (size_t)((og0 + g) * 16 + m15) * I0 + kof;
        ah[g] = *(const short8*)(wkh + off);
        al[g] = *(const short8*)(wkl + off);
      }
      short8 bhf[4], blf[4];
#pragma unroll
      for (int tg = 0; tg < 4; tg++) {
        int off = (tg * 16 + m15 + kw) * IPAD0 + kof;
        bhf[tg] = *(const short8*)(shi + off);
        blf[tg] = *(const short8*)(slo + off);
      }
#pragma unroll
      for (int g = 0; g < 2; g++)
#pragma unroll
        for (int tg = 0; tg < 4; tg++) {
          f32x4 d = dacc[g][tg];
          d = __builtin_amdgcn_mfma_f32_16x16x32_bf16(ah[g], bhf[tg], d, 0, 0, 0);
          d = __builtin_amdgcn_mfma_f32_16x16x32_bf16(ah[g], blf[tg], d, 0, 0, 0);
          d = __builtin_amdgcn_mfma_f32_16x16x32_bf16(al[g], bhf[tg], d, 0, 0, 0);
          dacc[g][tg] = d;
        }
    }
  }

  float* __restrict__ outb = out + (size_t)b * T * C;
  store_and_stats<2, 4>(dacc, outb, ssum, ssq, t0, og0, quad, m15);
  __syncthreads();
  int p = b * 8 + tile;
  if (tid < 128) {
    ps[tid * NPART + p] = ssum[tid];
    pq[tid * NPART + p] = ssq[tid];
  }
}

// ---------------------------------------------------------------------------
// Reduce partials -> mean, rstd per channel.
// ---------------------------------------------------------------------------
__device__ inline void reduce_one(const float* __restrict__ ps,
                                  const float* __restrict__ pq,
                                  float* __restrict__ om,
                                  float* __restrict__ orr, int c, int npart) {
  float s = 0.f, q = 0.f;
  for (int p = threadIdx.x; p < npart; p += 256) {
    s += ps[c * NPART + p];
    q += pq[c * NPART + p];
  }
  s = wave_sum(s);
  q = wave_sum(q);
  __shared__ float ls[8];
  int wv = threadIdx.x >> 6, ln = threadIdx.x & 63;
  if (ln == 0) { ls[wv] = s; ls[4 + wv] = q; }
  __syncthreads();
  if (threadIdx.x == 0) {
    float S = ls[0] + ls[1] + ls[2] + ls[3];
    float Q = ls[4] + ls[5] + ls[6] + ls[7];
    const float invn = 1.f / 64000.f;
    float m = S * invn;
    float v = Q * invn - m * m;
    om[c] = m;
    orr[c] = rsqrtf(v + 1e-5f);
  }
}

__global__ __launch_bounds__(256) void reduce_stats(
    const float* __restrict__ ps, const float* __restrict__ pq,
    float* __restrict__ om, float* __restrict__ orr, int npart) {
  reduce_one(ps, pq, om, orr, blockIdx.x, npart);
}

__global__ __launch_bounds__(256) void reduce_stats2(
    const float* __restrict__ psA, const float* __restrict__ pqA,
    float* __restrict__ omA, float* __restrict__ orA,
    const float* __restrict__ psB, const float* __restrict__ pqB,
    float* __restrict__ omB, float* __restrict__ orB, int npart) {
  if (blockIdx.y == 0)
    reduce_one(psA, pqA, omA, orA, blockIdx.x, npart);
  else
    reduce_one(psB, pqB, omB, orB, blockIdx.x, npart);
}

// ---------------------------------------------------------------------------
// In-place z = relu((z - m[c]) * r[c]) (used once, after conv0).
// ---------------------------------------------------------------------------
__global__ __launch_bounds__(256) void apply_bn_relu(
    float* __restrict__ x, const float* __restrict__ m,
    const float* __restrict__ r) {
  __shared__ float sm[C], sr[C];
  if (threadIdx.x < 128) {
    sm[threadIdx.x] = m[threadIdx.x];
    sr[threadIdx.x] = r[threadIdx.x];
  }
  __syncthreads();
  const size_t total4 = NBCT / 4;
  size_t stride = (size_t)gridDim.x * 256;
  for (size_t i4 = (size_t)blockIdx.x * 256 + threadIdx.x; i4 < total4;
       i4 += stride) {
    int c = (int)((i4 & 31) * 4);
    float4 v = ((float4*)x)[i4];
    v.x = fmaxf((v.x - sm[c]) * sr[c], 0.f);
    v.y = fmaxf((v.y - sm[c + 1]) * sr[c + 1], 0.f);
    v.z = fmaxf((v.z - sm[c + 2]) * sr[c + 2], 0.f);
    v.w = fmaxf((v.w - sm[c + 3]) * sr[c + 3], 0.f);
    ((float4*)x)[i4] = v;
  }
}

// ---------------------------------------------------------------------------
// combine: k = relu(bn2(t2) + relu(bn3(t3))); RK4 update.
// ---------------------------------------------------------------------------
__global__ __launch_bounds__(256) void combine_kernel(
    const float* __restrict__ t2, const float* __restrict__ t3,
    const float* __restrict__ m2, const float* __restrict__ r2,
    const float* __restrict__ m3, const float* __restrict__ r3,
    const float* __restrict__ z, float* __restrict__ acc,
    float* __restrict__ zout, float wacc, float anext, int init, int fin) {
  __shared__ float sm2[C], sr2[C], sm3[C], sr3[C];
  if (threadIdx.x < 128) {
    sm2[threadIdx.x] = m2[threadIdx.x];
    sr2[threadIdx.x] = r2[threadIdx.x];
    sm3[threadIdx.x] = m3[threadIdx.x];
    sr3[threadIdx.x] = r3[threadIdx.x];
  }
  __syncthreads();
  const size_t total4 = NBCT / 4;
  size_t stride = (size_t)gridDim.x * 256;
  for (size_t i4 = (size_t)blockIdx.x * 256 + threadIdx.x; i4 < total4;
       i4 += stride) {
    int c = (int)((i4 & 31) * 4);
    size_t off = i4 * 4;
    float4 v2 = *(const float4*)(t2 + off);
    float4 v3 = *(const float4*)(t3 + off);
    float4 vz = *(const float4*)(z + off);
    float4 k;
    k.x = fmaxf((v2.x - sm2[c]) * sr2[c] + fmaxf((v3.x - sm3[c]) * sr3[c], 0.f), 0.f);
    k.y = fmaxf((v2.y - sm2[c + 1]) * sr2[c + 1] + fmaxf((v3.y - sm3[c + 1]) * sr3[c + 1], 0.f), 0.f);
    k.z = fmaxf((v2.z - sm2[c + 2]) * sr2[c + 2] + fmaxf((v3.z - sm3[c + 2]) * sr3[c + 2], 0.f), 0.f);
    k.w = fmaxf((v2.w - sm2[c + 3]) * sr2[c + 3] + fmaxf((v3.w - sm3[c + 3]) * sr3[c + 3], 0.f), 0.f);
    float4 va;
    if (init) {
      va.x = wacc * k.x; va.y = wacc * k.y; va.z = wacc * k.z; va.w = wacc * k.w;
    } else {
      va = *(const float4*)(acc + off);
      va.x += wacc * k.x; va.y += wacc * k.y; va.z += wacc * k.z; va.w += wacc * k.w;
    }
    if (!fin) *(float4*)(acc + off) = va;
    float4 vo;
    if (fin) {
      vo.x = vz.x + anext * va.x; vo.y = vz.y + anext * va.y;
      vo.z = vz.z + anext * va.z; vo.w = vz.w + anext * va.w;
    } else {
      vo.x = vz.x + anext * k.x; vo.y = vz.y + anext * k.y;
      vo.z = vz.z + anext * k.z; vo.w = vz.w + anext * k.w;
    }
    *(float4*)(zout + off) = vo;
  }
}

// ---------------------------------------------------------------------------
// head, phase 1: partial t-sums. grid (B, 4), each block sums 125 t's.
// ---------------------------------------------------------------------------
__global__ __launch_bounds__(256) void feat_part(
    const float* __restrict__ z, float* __restrict__ fp) {
  const int b = blockIdx.x;
  const int s = blockIdx.y;
  const int c = threadIdx.x & 127;
  const int h = threadIdx.x >> 7;
  const float* zb = z + (size_t)b * T * C;
  float sum = 0.f;
  for (int t = s * 125 + h; t < (s + 1) * 125; t += 2)
    sum += zb[(size_t)t * C + c];
  __shared__ float sf[2][C];
  sf[h][c] = sum;
  __syncthreads();
  if (threadIdx.x < 128)
    fp[((size_t)b * 4 + s) * C + threadIdx.x] =
        sf[0][threadIdx.x] + sf[1][threadIdx.x];
}

// head, phase 2: feat = sum(partials)/500; out = feat @ ow^T + ob.
__global__ __launch_bounds__(256) void head2(
    const float* __restrict__ fp, const float* __restrict__ ow,
    const float* __restrict__ ob, float* __restrict__ out) {
  const int b = blockIdx.x;
  __shared__ float feat[C];
  if (threadIdx.x < 128) {
    float s = 0.f;
#pragma unroll
    for (int p = 0; p < 4; p++) s += fp[((size_t)b * 4 + p) * C + threadIdx.x];
    feat[threadIdx.x] = s * (1.f / 500.f);
  }
  __syncthreads();
  if (threadIdx.x < NL) {
    int l = threadIdx.x;
    float o = ob[l];
    for (int j = 0; j < C; j++) o = fmaf(feat[j], ow[l * C + j], o);
    out[b * NL + l] = o;
  }
}

// ---------------------------------------------------------------------------
extern "C" void kernel_launch(void* const* d_in, const int* in_sizes, int n_in,
                              void* d_out, int out_size, void* d_ws,
                              size_t ws_size, hipStream_t stream) {
  const float* x  = (const float*)d_in[0];
  const float* w0 = (const float*)d_in[1];
  const float* w1 = (const float*)d_in[2];
  const float* w2 = (const float*)d_in[3];
  const float* w3 = (const float*)d_in[4];
  const float* ow = (const float*)d_in[5];
  const float* ob = (const float*)d_in[6];
  float* out = (float*)d_out;

  static float *z, *acc, *zin, *t1, *t2, *t3;
  static float *ps1, *pq1, *ps2, *pq2, *ps3, *pq3;
  static float *m1, *r1, *m2, *r2, *m3, *r3, *featp;
  static unsigned short *w0h, *w0l, *w1h, *w1l, *w2h, *w2l, *w3h, *w3l;
  static bool inited = false;
  if (!inited) {
    void* p;
#define GET(sym, var) hipGetSymbolAddress(&p, HIP_SYMBOL(sym)); var = (decltype(var))p;
    GET(g_z, z) GET(g_acc, acc) GET(g_zin, zin)
    GET(g_t1, t1) GET(g_t2, t2) GET(g_t3, t3)
    GET(g_ps1, ps1) GET(g_pq1, pq1) GET(g_ps2, ps2) GET(g_pq2, pq2)
    GET(g_ps3, ps3) GET(g_pq3, pq3)
    GET(g_m1, m1) GET(g_r1, r1) GET(g_m2, m2) GET(g_r2, r2)
    GET(g_m3, m3) GET(g_r3, r3) GET(g_featp, featp)
    GET(g_w0h, w0h) GET(g_w0l, w0l)
    GET(g_w1h, w1h) GET(g_w1l, w1l) GET(g_w2h, w2h) GET(g_w2l, w2l)
    GET(g_w3h, w3h) GET(g_w3l, w3l)
#undef GET
    inited = true;
  }

  // Weight prep (cheap, every launch)
  prep_w0<<<(3 * C * I0 + 255) / 256, 256, 0, stream>>>(w0, w0h, w0l);
  prep_weights_v4<9><<<(C * C * 9 + 255) / 256, 256, 0, stream>>>(w1, w1h, w1l);
  prep_weights_v4<9><<<(C * C * 9 + 255) / 256, 256, 0, stream>>>(w2, w2h, w2l);
  prep_weights_v4<1><<<(C * C * 1 + 255) / 256, 256, 0, stream>>>(w3, w3h, w3l);

  const dim3 convGrid(8, B);   // NT=64 tiles -> 1024 blocks = 4/CU resident
  const int ewGrid = 1024;
  const float dt = 0.25f;

  // conv0 -> bn -> relu (into z)
  conv0_mfma<<<convGrid, 256, 0, stream>>>(x, w0h, w0l, z, ps1, pq1);
  reduce_stats<<<C, 256, 0, stream>>>(ps1, pq1, m1, r1, 1024);
  apply_bn_relu<<<ewGrid, 256, 0, stream>>>(z, m1, r1);

  const float waccs[4] = {1.f, 2.f, 2.f, 1.f};
  const float anexts[4] = {0.5f * dt, 0.5f * dt, dt, dt / 6.f};

  for (int step = 0; step < 4; step++) {
    for (int s = 0; s < 4; s++) {
      const float* zin_s = (s == 0) ? z : zin;
      conv_v6<9, 4, false><<<convGrid, 256, 0, stream>>>(
          zin_s, w1h, w1l, nullptr, nullptr, t1, ps1, pq1);
      conv_v6<1, 0, false><<<convGrid, 256, 0, stream>>>(
          zin_s, w3h, w3l, nullptr, nullptr, t3, ps3, pq3);
      reduce_stats2<<<dim3(C, 2), 256, 0, stream>>>(
          ps1, pq1, m1, r1, ps3, pq3, m3, r3, 1024);
      conv_v6<9, 4, true><<<convGrid, 256, 0, stream>>>(
          t1, w2h, w2l, m1, r1, t2, ps2, pq2);
      reduce_stats<<<C, 256, 0, stream>>>(ps2, pq2, m2, r2, 1024);
      combine_kernel<<<ewGrid, 256, 0, stream>>>(
          t2, t3, m2, r2, m3, r3, z, acc, (s == 3) ? z : zin,
          waccs[s], anexts[s], (s == 0) ? 1 : 0, (s == 3) ? 1 : 0);
    }
  }

  feat_part<<<dim3(B, 4), 256, 0, stream>>>(z, featp);
  head2<<<B, 256, 0, stream>>>(featp, ow, ob, out);
}

// Round 9
// 2689.519 us; speedup vs baseline: 1.3160x; 1.3160x over previous
//
#include <hip/hip_runtime.h>
#include <hip/hip_bf16.h>
#include <cstddef>

// Problem constants
constexpr int B = 128;
constexpr int T = 500;
constexpr int C = 128;     // n_maps
constexpr int CIN = 80;    // n_mels
constexpr int NL = 35;     // labels
constexpr size_t NBCT = (size_t)B * C * T;  // 8,192,000 floats
constexpr int NPART = 1024;                 // partial-stats buffer stride
constexpr int WPAD = 132;                   // LDS i-stride (0 bank conflicts, measured R4)
constexpr int I0 = 96;                      // conv0 padded input channels
constexpr int IPAD0 = 104;                  // conv0 LDS i-stride
constexpr int NT = 64;                      // conv t-tile (4 blocks/CU resident)

typedef __attribute__((ext_vector_type(8))) short short8;    // 8 bf16
typedef __attribute__((ext_vector_type(4))) float f32x4;

// Static device scratch. All activation tensors in [b][t][c] layout.
__device__ float g_z[NBCT];
__device__ float g_acc[NBCT];
__device__ float g_zin[NBCT];
__device__ float g_t1[NBCT];
__device__ float g_t2[NBCT];
__device__ float g_t3[NBCT];
__device__ float g_ps1[C * NPART], g_pq1[C * NPART];
__device__ float g_ps2[C * NPART], g_pq2[C * NPART];
__device__ float g_ps3[C * NPART], g_pq3[C * NPART];
__device__ float g_m1[C], g_r1[C], g_m2[C], g_r2[C], g_m3[C], g_r3[C];
__device__ float g_featp[B * 4 * C];        // head partial sums
// conv0 weights, layout [kw][o][i] (i-stride I0)
__device__ unsigned short g_w0h[3 * C * I0], g_w0l[3 * C * I0];
// main conv weights, MFMA-native layout [kw][kseg=i>>3][o][j=i&7]
__device__ unsigned short g_w1h[9 * C * C], g_w1l[9 * C * C];
__device__ unsigned short g_w2h[9 * C * C], g_w2l[9 * C * C];
__device__ unsigned short g_w3h[1 * C * C], g_w3l[1 * C * C];

__device__ inline unsigned short f2bf(float x) {
  __hip_bfloat16 h = __float2bfloat16(x);
  return *(unsigned short*)&h;
}
__device__ inline float bf2f(unsigned short u) {
  __hip_bfloat16 h = *(__hip_bfloat16*)&u;
  return __bfloat162float(h);
}
__device__ inline void split_bf16(float x, unsigned short& h, unsigned short& l) {
  unsigned short hh = f2bf(x);
  h = hh;
  l = f2bf(x - bf2f(hh));
}

__inline__ __device__ float wave_sum(float v) {
  for (int off = 32; off; off >>= 1) v += __shfl_down(v, off);
  return v;
}

// ---------------------------------------------------------------------------
// Weight prep: w [O][I][KW] fp32 -> hi/lo bf16, layout [kw][i>>3][o][i&7]
// (A-frag loads become 16-lane-contiguous 256B runs)
// ---------------------------------------------------------------------------
template <int KW>
__global__ __launch_bounds__(256) void prep_weights_v4(
    const float* __restrict__ w, unsigned short* __restrict__ wh,
    unsigned short* __restrict__ wl) {
  int idx = blockIdx.x * 256 + threadIdx.x;
  if (idx >= C * C * KW) return;
  int kw = idx % KW;
  int i = (idx / KW) % C;
  int o = idx / (KW * C);
  unsigned short h, l;
  split_bf16(w[idx], h, l);
  size_t dst = (((size_t)kw * 16 + (i >> 3)) * C + o) * 8 + (i & 7);
  wh[dst] = h;
  wl[dst] = l;
}

// conv0 weights: w0 [O=128][I=80][3] -> [3][O][I0=96] (zero-padded i>=80)
__global__ __launch_bounds__(256) void prep_w0(
    const float* __restrict__ w, unsigned short* __restrict__ wh,
    unsigned short* __restrict__ wl) {
  int idx = blockIdx.x * 256 + threadIdx.x;
  if (idx >= 3 * C * I0) return;
  int i = idx % I0;
  int o = (idx / I0) % C;
  int kw = idx / (I0 * C);
  unsigned short h = 0, l = 0;
  if (i < CIN) split_bf16(w[((size_t)o * CIN + i) * 3 + kw], h, l);
  size_t dst = ((size_t)kw * C + o) * I0 + i;
  wh[dst] = h;
  wl[dst] = l;
}

// ---------------------------------------------------------------------------
// Epilogue: store D tiles + per-channel partial stats into LDS ssum/ssq.
// D layout (16x16x32): col(t)=lane&15, row(o)=quad*4+reg.
// ---------------------------------------------------------------------------
template <int NG, int NTG>
__device__ inline void store_and_stats(f32x4 (&dacc)[NG][NTG],
                                       float* __restrict__ outb,
                                       float* __restrict__ ssum,
                                       float* __restrict__ ssq, int tbase,
                                       int og0, int quad, int m15) {
#pragma unroll
  for (int g = 0; g < NG; g++) {
    float rs[4] = {0.f, 0.f, 0.f, 0.f}, rq[4] = {0.f, 0.f, 0.f, 0.f};
#pragma unroll
    for (int tg = 0; tg < NTG; tg++) {
      int t = tbase + tg * 16 + m15;
      bool valid = t < T;
      f32x4 d = dacc[g][tg];
      if (valid)
        *(f32x4*)(outb + (size_t)t * C + (og0 + g) * 16 + quad * 4) = d;
#pragma unroll
      for (int r = 0; r < 4; r++) {
        float v = valid ? d[r] : 0.f;
        rs[r] += v;
        rq[r] += v * v;
      }
    }
#pragma unroll
    for (int sh = 1; sh < 16; sh <<= 1) {
#pragma unroll
      for (int r = 0; r < 4; r++) {
        rs[r] += __shfl_xor(rs[r], sh);
        rq[r] += __shfl_xor(rq[r], sh);
      }
    }
    if (m15 == 0) {
      int o = (og0 + g) * 16 + quad * 4;
#pragma unroll
      for (int r = 0; r < 4; r++) {
        atomicAdd(&ssum[o + r], rs[r]);
        atomicAdd(&ssq[o + r], rq[r]);
      }
    }
  }
}

// ---------------------------------------------------------------------------
// Main MFMA conv (v5, the R7 winner): NT=64, 16x16x32 bf16x3, 4 waves x
// (2 og x 4 tg). Grid (8, B) = 1024 blocks = 4/CU resident (LDS ~40 KB,
// VGPR <= 128 via launch_bounds(256,4)). MFMA-native coalesced A layout.
// ---------------------------------------------------------------------------
template <int KW, int PAD, bool BNRELU>
__global__ __launch_bounds__(256, 4) void conv_v5(
    const float* __restrict__ in, const unsigned short* __restrict__ wh,
    const unsigned short* __restrict__ wl, const float* __restrict__ bnm,
    const float* __restrict__ bnr, float* __restrict__ out,
    float* __restrict__ ps, float* __restrict__ pq) {
  constexpr int ROWS = NT + KW - 1;
  __shared__ __align__(16) unsigned short shi[ROWS * WPAD];
  __shared__ __align__(16) unsigned short slo[ROWS * WPAD];
  __shared__ float ssum[C], ssq[C];
  __shared__ float sbm[C], sbr[C];

  const int tid = threadIdx.x;
  const int tile = blockIdx.x;
  const int b = blockIdx.y;
  const int t0 = tile * NT;

  if (BNRELU) {
    if (tid < 128) { sbm[tid] = bnm[tid]; sbr[tid] = bnr[tid]; }
  }
  if (tid < 128) { ssum[tid] = 0.f; ssq[tid] = 0.f; }
  __syncthreads();

  // Stage input rows [t0-PAD, t0-PAD+ROWS) as bf16 hi/lo into LDS.
  const float* __restrict__ inb = in + (size_t)b * T * C;
  constexpr int NF4 = ROWS * (C / 4);
  for (int e = tid; e < NF4; e += 256) {
    int r = e >> 5;
    int c4 = e & 31;
    int t = t0 - PAD + r;
    float4 v = make_float4(0.f, 0.f, 0.f, 0.f);
    if (t >= 0 && t < T) v = ((const float4*)(inb + (size_t)t * C))[c4];
    if (BNRELU) {
      int c = c4 * 4;
      v.x = fmaxf((v.x - sbm[c]) * sbr[c], 0.f);
      v.y = fmaxf((v.y - sbm[c + 1]) * sbr[c + 1], 0.f);
      v.z = fmaxf((v.z - sbm[c + 2]) * sbr[c + 2], 0.f);
      v.w = fmaxf((v.w - sbm[c + 3]) * sbr[c + 3], 0.f);
    }
    ushort4 hv, lv;
    split_bf16(v.x, hv.x, lv.x);
    split_bf16(v.y, hv.y, lv.y);
    split_bf16(v.z, hv.z, lv.z);
    split_bf16(v.w, hv.w, lv.w);
    int off = r * WPAD + c4 * 4;
    *(ushort4*)&shi[off] = hv;
    *(ushort4*)&slo[off] = lv;
  }
  __syncthreads();

  const int wv = tid >> 6;
  const int lane = tid & 63;
  const int quad = lane >> 4;
  const int m15 = lane & 15;
  const int og0 = wv * 2;

  const short8* __restrict__ Ah = (const short8*)wh;
  const short8* __restrict__ Al = (const short8*)wl;

  f32x4 dacc[2][4];
#pragma unroll
  for (int g = 0; g < 2; g++)
#pragma unroll
    for (int tg = 0; tg < 4; tg++) dacc[g][tg] = f32x4{0.f, 0.f, 0.f, 0.f};

  for (int kw = 0; kw < KW; kw++) {
#pragma unroll
    for (int ic = 0; ic < 4; ic++) {
      const int kof = ic * 32 + quad * 8;
      // A-frags: MFMA-native layout, 16-lane contiguous 256B runs
      short8 ah[2], al[2];
#pragma unroll
      for (int g = 0; g < 2; g++) {
        int ai = (kw * 16 + ic * 4 + quad) * C + (og0 + g) * 16 + m15;
        ah[g] = Ah[ai];
        al[g] = Al[ai];
      }
      short8 bhf[4], blf[4];
#pragma unroll
      for (int tg = 0; tg < 4; tg++) {
        int off = (tg * 16 + m15 + kw) * WPAD + kof;
        bhf[tg] = *(const short8*)(shi + off);
        blf[tg] = *(const short8*)(slo + off);
      }
#pragma unroll
      for (int g = 0; g < 2; g++)
#pragma unroll
        for (int tg = 0; tg < 4; tg++) {
          f32x4 d = dacc[g][tg];
          d = __builtin_amdgcn_mfma_f32_16x16x32_bf16(ah[g], bhf[tg], d, 0, 0, 0);
          d = __builtin_amdgcn_mfma_f32_16x16x32_bf16(ah[g], blf[tg], d, 0, 0, 0);
          d = __builtin_amdgcn_mfma_f32_16x16x32_bf16(al[g], bhf[tg], d, 0, 0, 0);
          dacc[g][tg] = d;
        }
    }
  }

  float* __restrict__ outb = out + (size_t)b * T * C;
  store_and_stats<2, 4>(dacc, outb, ssum, ssq, t0, og0, quad, m15);
  __syncthreads();
  int p = b * 8 + tile;
  if (tid < 128) {
    ps[tid * NPART + p] = ssum[tid];
    pq[tid * NPART + p] = ssq[tid];
  }
}

// ---------------------------------------------------------------------------
// conv0: 16x16x32 MFMA bf16x3. in x[B][80][T] (t fastest), K=96(pad) x 3.
// ---------------------------------------------------------------------------
__global__ __launch_bounds__(256) void conv0_mfma(
    const float* __restrict__ in, const unsigned short* __restrict__ wh,
    const unsigned short* __restrict__ wl, float* __restrict__ out,
    float* __restrict__ ps, float* __restrict__ pq) {
  constexpr int KW = 3, PAD = 1;
  constexpr int ROWS = NT + KW - 1;  // 66
  __shared__ __align__(16) unsigned short shi[ROWS * IPAD0];
  __shared__ __align__(16) unsigned short slo[ROWS * IPAD0];
  __shared__ float ssum[C], ssq[C];

  const int tid = threadIdx.x;
  const int tile = blockIdx.x;
  const int b = blockIdx.y;
  const int t0 = tile * NT;

  if (tid < 128) { ssum[tid] = 0.f; ssq[tid] = 0.f; }
  __syncthreads();

  const float* __restrict__ inb = in + (size_t)b * CIN * T;
  for (int e = tid; e < I0 * ROWS; e += 256) {
    int i = e / ROWS;
    int r = e % ROWS;
    int t = t0 - PAD + r;
    float v = 0.f;
    if (i < CIN && t >= 0 && t < T) v = inb[(size_t)i * T + t];
    unsigned short h, l;
    split_bf16(v, h, l);
    shi[r * IPAD0 + i] = h;
    slo[r * IPAD0 + i] = l;
  }
  __syncthreads();

  const int wv = tid >> 6;
  const int lane = tid & 63;
  const int quad = lane >> 4;
  const int m15 = lane & 15;
  const int og0 = wv * 2;

  f32x4 dacc[2][4];
#pragma unroll
  for (int g = 0; g < 2; g++)
#pragma unroll
    for (int tg = 0; tg < 4; tg++) dacc[g][tg] = f32x4{0.f, 0.f, 0.f, 0.f};

  for (int kw = 0; kw < KW; kw++) {
    const unsigned short* __restrict__ wkh = wh + (size_t)kw * C * I0;
    const unsigned short* __restrict__ wkl = wl + (size_t)kw * C * I0;
#pragma unroll
    for (int ic = 0; ic < 3; ic++) {
      const int kof = ic * 32 + quad * 8;
      short8 ah[2], al[2];
#pragma unroll
      for (int g = 0; g < 2; g++) {
        size_t off = (size_t)((og0 + g) * 16 + m15) * I0 + kof;
        ah[g] = *(const short8*)(wkh + off);
        al[g] = *(const short8*)(wkl + off);
      }
      short8 bhf[4], blf[4];
#pragma unroll
      for (int tg = 0; tg < 4; tg++) {
        int off = (tg * 16 + m15 + kw) * IPAD0 + kof;
        bhf[tg] = *(const short8*)(shi + off);
        blf[tg] = *(const short8*)(slo + off);
      }
#pragma unroll
      for (int g = 0; g < 2; g++)
#pragma unroll
        for (int tg = 0; tg < 4; tg++) {
          f32x4 d = dacc[g][tg];
          d = __builtin_amdgcn_mfma_f32_16x16x32_bf16(ah[g], bhf[tg], d, 0, 0, 0);
          d = __builtin_amdgcn_mfma_f32_16x16x32_bf16(ah[g], blf[tg], d, 0, 0, 0);
          d = __builtin_amdgcn_mfma_f32_16x16x32_bf16(al[g], bhf[tg], d, 0, 0, 0);
          dacc[g][tg] = d;
        }
    }
  }

  float* __restrict__ outb = out + (size_t)b * T * C;
  store_and_stats<2, 4>(dacc, outb, ssum, ssq, t0, og0, quad, m15);
  __syncthreads();
  int p = b * 8 + tile;
  if (tid < 128) {
    ps[tid * NPART + p] = ssum[tid];
    pq[tid * NPART + p] = ssq[tid];
  }
}

// ---------------------------------------------------------------------------
// Reduce partials -> mean, rstd per channel.
// ---------------------------------------------------------------------------
__device__ inline void reduce_one(const float* __restrict__ ps,
                                  const float* __restrict__ pq,
                                  float* __restrict__ om,
                                  float* __restrict__ orr, int c, int npart) {
  float s = 0.f, q = 0.f;
  for (int p = threadIdx.x; p < npart; p += 256) {
    s += ps[c * NPART + p];
    q += pq[c * NPART + p];
  }
  s = wave_sum(s);
  q = wave_sum(q);
  __shared__ float ls[8];
  int wv = threadIdx.x >> 6, ln = threadIdx.x & 63;
  if (ln == 0) { ls[wv] = s; ls[4 + wv] = q; }
  __syncthreads();
  if (threadIdx.x == 0) {
    float S = ls[0] + ls[1] + ls[2] + ls[3];
    float Q = ls[4] + ls[5] + ls[6] + ls[7];
    const float invn = 1.f / 64000.f;
    float m = S * invn;
    float v = Q * invn - m * m;
    om[c] = m;
    orr[c] = rsqrtf(v + 1e-5f);
  }
}

__global__ __launch_bounds__(256) void reduce_stats(
    const float* __restrict__ ps, const float* __restrict__ pq,
    float* __restrict__ om, float* __restrict__ orr, int npart) {
  reduce_one(ps, pq, om, orr, blockIdx.x, npart);
}

__global__ __launch_bounds__(256) void reduce_stats2(
    const float* __restrict__ psA, const float* __restrict__ pqA,
    float* __restrict__ omA, float* __restrict__ orA,
    const float* __restrict__ psB, const float* __restrict__ pqB,
    float* __restrict__ omB, float* __restrict__ orB, int npart) {
  if (blockIdx.y == 0)
    reduce_one(psA, pqA, omA, orA, blockIdx.x, npart);
  else
    reduce_one(psB, pqB, omB, orB, blockIdx.x, npart);
}

// ---------------------------------------------------------------------------
// In-place z = relu((z - m[c]) * r[c]) (used once, after conv0).
// ---------------------------------------------------------------------------
__global__ __launch_bounds__(256) void apply_bn_relu(
    float* __restrict__ x, const float* __restrict__ m,
    const float* __restrict__ r) {
  __shared__ float sm[C], sr[C];
  if (threadIdx.x < 128) {
    sm[threadIdx.x] = m[threadIdx.x];
    sr[threadIdx.x] = r[threadIdx.x];
  }
  __syncthreads();
  const size_t total4 = NBCT / 4;
  size_t stride = (size_t)gridDim.x * 256;
  for (size_t i4 = (size_t)blockIdx.x * 256 + threadIdx.x; i4 < total4;
       i4 += stride) {
    int c = (int)((i4 & 31) * 4);
    float4 v = ((float4*)x)[i4];
    v.x = fmaxf((v.x - sm[c]) * sr[c], 0.f);
    v.y = fmaxf((v.y - sm[c + 1]) * sr[c + 1], 0.f);
    v.z = fmaxf((v.z - sm[c + 2]) * sr[c + 2], 0.f);
    v.w = fmaxf((v.w - sm[c + 3]) * sr[c + 3], 0.f);
    ((float4*)x)[i4] = v;
  }
}

// ---------------------------------------------------------------------------
// combine: k = relu(bn2(t2) + relu(bn3(t3))); RK4 update.
// ---------------------------------------------------------------------------
__global__ __launch_bounds__(256) void combine_kernel(
    const float* __restrict__ t2, const float* __restrict__ t3,
    const float* __restrict__ m2, const float* __restrict__ r2,
    const float* __restrict__ m3, const float* __restrict__ r3,
    const float* __restrict__ z, float* __restrict__ acc,
    float* __restrict__ zout, float wacc, float anext, int init, int fin) {
  __shared__ float sm2[C], sr2[C], sm3[C], sr3[C];
  if (threadIdx.x < 128) {
    sm2[threadIdx.x] = m2[threadIdx.x];
    sr2[threadIdx.x] = r2[threadIdx.x];
    sm3[threadIdx.x] = m3[threadIdx.x];
    sr3[threadIdx.x] = r3[threadIdx.x];
  }
  __syncthreads();
  const size_t total4 = NBCT / 4;
  size_t stride = (size_t)gridDim.x * 256;
  for (size_t i4 = (size_t)blockIdx.x * 256 + threadIdx.x; i4 < total4;
       i4 += stride) {
    int c = (int)((i4 & 31) * 4);
    size_t off = i4 * 4;
    float4 v2 = *(const float4*)(t2 + off);
    float4 v3 = *(const float4*)(t3 + off);
    float4 vz = *(const float4*)(z + off);
    float4 k;
    k.x = fmaxf((v2.x - sm2[c]) * sr2[c] + fmaxf((v3.x - sm3[c]) * sr3[c], 0.f), 0.f);
    k.y = fmaxf((v2.y - sm2[c + 1]) * sr2[c + 1] + fmaxf((v3.y - sm3[c + 1]) * sr3[c + 1], 0.f), 0.f);
    k.z = fmaxf((v2.z - sm2[c + 2]) * sr2[c + 2] + fmaxf((v3.z - sm3[c + 2]) * sr3[c + 2], 0.f), 0.f);
    k.w = fmaxf((v2.w - sm2[c + 3]) * sr2[c + 3] + fmaxf((v3.w - sm3[c + 3]) * sr3[c + 3], 0.f), 0.f);
    float4 va;
    if (init) {
      va.x = wacc * k.x; va.y = wacc * k.y; va.z = wacc * k.z; va.w = wacc * k.w;
    } else {
      va = *(const float4*)(acc + off);
      va.x += wacc * k.x; va.y += wacc * k.y; va.z += wacc * k.z; va.w += wacc * k.w;
    }
    if (!fin) *(float4*)(acc + off) = va;
    float4 vo;
    if (fin) {
      vo.x = vz.x + anext * va.x; vo.y = vz.y + anext * va.y;
      vo.z = vz.z + anext * va.z; vo.w = vz.w + anext * va.w;
    } else {
      vo.x = vz.x + anext * k.x; vo.y = vz.y + anext * k.y;
      vo.z = vz.z + anext * k.z; vo.w = vz.w + anext * k.w;
    }
    *(float4*)(zout + off) = vo;
  }
}

// ---------------------------------------------------------------------------
// head, phase 1: partial t-sums. grid (B, 4), each block sums 125 t's.
// ---------------------------------------------------------------------------
__global__ __launch_bounds__(256) void feat_part(
    const float* __restrict__ z, float* __restrict__ fp) {
  const int b = blockIdx.x;
  const int s = blockIdx.y;
  const int c = threadIdx.x & 127;
  const int h = threadIdx.x >> 7;
  const float* zb = z + (size_t)b * T * C;
  float sum = 0.f;
  for (int t = s * 125 + h; t < (s + 1) * 125; t += 2)
    sum += zb[(size_t)t * C + c];
  __shared__ float sf[2][C];
  sf[h][c] = sum;
  __syncthreads();
  if (threadIdx.x < 128)
    fp[((size_t)b * 4 + s) * C + threadIdx.x] =
        sf[0][threadIdx.x] + sf[1][threadIdx.x];
}

// head, phase 2: feat = sum(partials)/500; out = feat @ ow^T + ob.
__global__ __launch_bounds__(256) void head2(
    const float* __restrict__ fp, const float* __restrict__ ow,
    const float* __restrict__ ob, float* __restrict__ out) {
  const int b = blockIdx.x;
  __shared__ float feat[C];
  if (threadIdx.x < 128) {
    float s = 0.f;
#pragma unroll
    for (int p = 0; p < 4; p++) s += fp[((size_t)b * 4 + p) * C + threadIdx.x];
    feat[threadIdx.x] = s * (1.f / 500.f);
  }
  __syncthreads();
  if (threadIdx.x < NL) {
    int l = threadIdx.x;
    float o = ob[l];
    for (int j = 0; j < C; j++) o = fmaf(feat[j], ow[l * C + j], o);
    out[b * NL + l] = o;
  }
}

// ---------------------------------------------------------------------------
extern "C" void kernel_launch(void* const* d_in, const int* in_sizes, int n_in,
                              void* d_out, int out_size, void* d_ws,
                              size_t ws_size, hipStream_t stream) {
  const float* x  = (const float*)d_in[0];
  const float* w0 = (const float*)d_in[1];
  const float* w1 = (const float*)d_in[2];
  const float* w2 = (const float*)d_in[3];
  const float* w3 = (const float*)d_in[4];
  const float* ow = (const float*)d_in[5];
  const float* ob = (const float*)d_in[6];
  float* out = (float*)d_out;

  static float *z, *acc, *zin, *t1, *t2, *t3;
  static float *ps1, *pq1, *ps2, *pq2, *ps3, *pq3;
  static float *m1, *r1, *m2, *r2, *m3, *r3, *featp;
  static unsigned short *w0h, *w0l, *w1h, *w1l, *w2h, *w2l, *w3h, *w3l;
  static bool inited = false;
  if (!inited) {
    void* p;
#define GET(sym, var) hipGetSymbolAddress(&p, HIP_SYMBOL(sym)); var = (decltype(var))p;
    GET(g_z, z) GET(g_acc, acc) GET(g_zin, zin)
    GET(g_t1, t1) GET(g_t2, t2) GET(g_t3, t3)
    GET(g_ps1, ps1) GET(g_pq1, pq1) GET(g_ps2, ps2) GET(g_pq2, pq2)
    GET(g_ps3, ps3) GET(g_pq3, pq3)
    GET(g_m1, m1) GET(g_r1, r1) GET(g_m2, m2) GET(g_r2, r2)
    GET(g_m3, m3) GET(g_r3, r3) GET(g_featp, featp)
    GET(g_w0h, w0h) GET(g_w0l, w0l)
    GET(g_w1h, w1h) GET(g_w1l, w1l) GET(g_w2h, w2h) GET(g_w2l, w2l)
    GET(g_w3h, w3h) GET(g_w3l, w3l)
#undef GET
    inited = true;
  }

  // Weight prep (cheap, every launch)
  prep_w0<<<(3 * C * I0 + 255) / 256, 256, 0, stream>>>(w0, w0h, w0l);
  prep_weights_v4<9><<<(C * C * 9 + 255) / 256, 256, 0, stream>>>(w1, w1h, w1l);
  prep_weights_v4<9><<<(C * C * 9 + 255) / 256, 256, 0, stream>>>(w2, w2h, w2l);
  prep_weights_v4<1><<<(C * C * 1 + 255) / 256, 256, 0, stream>>>(w3, w3h, w3l);

  const dim3 convGrid(8, B);   // NT=64 tiles -> 1024 blocks = 4/CU resident
  const int ewGrid = 1024;
  const float dt = 0.25f;

  // conv0 -> bn -> relu (into z)
  conv0_mfma<<<convGrid, 256, 0, stream>>>(x, w0h, w0l, z, ps1, pq1);
  reduce_stats<<<C, 256, 0, stream>>>(ps1, pq1, m1, r1, 1024);
  apply_bn_relu<<<ewGrid, 256, 0, stream>>>(z, m1, r1);

  const float waccs[4] = {1.f, 2.f, 2.f, 1.f};
  const float anexts[4] = {0.5f * dt, 0.5f * dt, dt, dt / 6.f};

  for (int step = 0; step < 4; step++) {
    for (int s = 0; s < 4; s++) {
      const float* zin_s = (s == 0) ? z : zin;
      conv_v5<9, 4, false><<<convGrid, 256, 0, stream>>>(
          zin_s, w1h, w1l, nullptr, nullptr, t1, ps1, pq1);
      conv_v5<1, 0, false><<<convGrid, 256, 0, stream>>>(
          zin_s, w3h, w3l, nullptr, nullptr, t3, ps3, pq3);
      reduce_stats2<<<dim3(C, 2), 256, 0, stream>>>(
          ps1, pq1, m1, r1, ps3, pq3, m3, r3, 1024);
      conv_v5<9, 4, true><<<convGrid, 256, 0, stream>>>(
          t1, w2h, w2l, m1, r1, t2, ps2, pq2);
      reduce_stats<<<C, 256, 0, stream>>>(ps2, pq2, m2, r2, 1024);
      combine_kernel<<<ewGrid, 256, 0, stream>>>(
          t2, t3, m2, r2, m3, r3, z, acc, (s == 3) ? z : zin,
          waccs[s], anexts[s], (s == 0) ? 1 : 0, (s == 3) ? 1 : 0);
    }
  }

  feat_part<<<dim3(B, 4), 256, 0, stream>>>(z, featp);
  head2<<<B, 256, 0, stream>>>(featp, ow, ob, out);
}